// Round 2
// baseline (199.339 us; speedup 1.0000x reference)
//
#include <hip/hip_runtime.h>
#include <hip/hip_bf16.h>

#define BB 16
#define CIN 16
#define COUT 32
#define EDG 60000
#define NE (BB * EDG)            // 960000 edges
#define YELEMS (BB * COUT * EDG) // 30,720,000 f32 out elems for y
#define GELEMS (NE * 4)          // 3,840,000 f32 out elems for gemm
#define EPS 1e-5f

typedef unsigned short us8 __attribute__((ext_vector_type(8)));

// round-to-nearest-even f32 -> bf16 bits
static __device__ __forceinline__ unsigned short f2bf(float f) {
    unsigned u = __float_as_uint(f);
    return (unsigned short)((u + 0x7FFFu + ((u >> 16) & 1u)) >> 16);
}
static __device__ __forceinline__ float bf2f(unsigned short h) {
    return __uint_as_float(((unsigned)h) << 16);
}

// xt[b][e][c] = bf16(x[b][c][e])  -> each edge's 16 channels = one 32B row
__global__ __launch_bounds__(256) void k_transpose(const float* __restrict__ x,
                                                   unsigned short* __restrict__ xt) {
    int idx = blockIdx.x * 256 + threadIdx.x;
    if (idx >= NE) return;
    int b = idx / EDG, e = idx - b * EDG;
    const float* xp = x + (size_t)b * CIN * EDG + e;
    float v[CIN];
#pragma unroll
    for (int c = 0; c < CIN; ++c) v[c] = xp[(size_t)c * EDG];
    us8* o = reinterpret_cast<us8*>(xt + (size_t)idx * CIN);
#pragma unroll
    for (int h = 0; h < 2; ++h) {
        us8 r;
#pragma unroll
        for (int j = 0; j < 8; ++j) r[j] = f2bf(v[8 * h + j]);
        o[h] = r;
    }
}

// pass-through mesh: gemm int -> f32 in output tail (exact: indices < 2^24)
__global__ __launch_bounds__(256) void k_gemmcopy(const int* __restrict__ g,
                                                  float* __restrict__ og) {
    int i = blockIdx.x * 256 + threadIdx.x;
    if (i >= GELEMS / 4) return;
    int4 v = reinterpret_cast<const int4*>(g)[i];
    reinterpret_cast<float4*>(og)[i] =
        make_float4((float)v.x, (float)v.y, (float)v.z, (float)v.w);
}

// mesh conv: gather 4 neighbor rows + self, build 5 symmetric feats, contract
// with w[32][16][5]. Weight indices are compile-time after unroll -> s_load path.
// bias skipped: per-channel constant cancels exactly under train-mode BatchNorm.
template <bool WSY>
__global__ __launch_bounds__(256) void k_conv(const unsigned short* __restrict__ xt,
                                              const int* __restrict__ gemm,
                                              const float* __restrict__ w,
                                              unsigned short* __restrict__ yb,
                                              float* __restrict__ yf) {
    int idx = blockIdx.x * 256 + threadIdx.x;
    if (idx >= NE) return;
    int b = idx / EDG, e = idx - b * EDG;

    int4 g = reinterpret_cast<const int4*>(gemm)[idx];
    const us8* self = reinterpret_cast<const us8*>(xt + (size_t)idx * CIN);
    const us8* p0 = reinterpret_cast<const us8*>(xt + ((size_t)b * EDG + g.x) * CIN);
    const us8* p1 = reinterpret_cast<const us8*>(xt + ((size_t)b * EDG + g.y) * CIN);
    const us8* p2 = reinterpret_cast<const us8*>(xt + ((size_t)b * EDG + g.z) * CIN);
    const us8* p3 = reinterpret_cast<const us8*>(xt + ((size_t)b * EDG + g.w) * CIN);

    float acc[COUT];
#pragma unroll
    for (int o = 0; o < COUT; ++o) acc[o] = 0.f;

#pragma unroll
    for (int h = 0; h < 2; ++h) {  // two 8-channel halves
        us8 xs = self[h], av = p0[h], bv = p1[h], cv = p2[h], dv = p3[h];
        float f0[8], f1[8], f2[8], f3[8], f4[8];
#pragma unroll
        for (int j = 0; j < 8; ++j) {
            float xf = bf2f(xs[j]);
            float a = bf2f(av[j]), bq = bf2f(bv[j]);
            float c = bf2f(cv[j]), d = bf2f(dv[j]);
            f0[j] = xf;
            f1[j] = a + c;
            f2[j] = fabsf(a - c);
            f3[j] = bq + d;
            f4[j] = fabsf(bq - d);
        }
#pragma unroll
        for (int o = 0; o < COUT; ++o) {
            const float* wo = w + o * (CIN * 5) + h * 40;
            float s = acc[o];
#pragma unroll
            for (int j = 0; j < 8; ++j) {
                s = fmaf(wo[j * 5 + 0], f0[j], s);
                s = fmaf(wo[j * 5 + 1], f1[j], s);
                s = fmaf(wo[j * 5 + 2], f2[j], s);
                s = fmaf(wo[j * 5 + 3], f3[j], s);
                s = fmaf(wo[j * 5 + 4], f4[j], s);
            }
            acc[o] = s;
        }
    }

    size_t base = (size_t)b * COUT * EDG + e;
    if constexpr (WSY) {
#pragma unroll
        for (int o = 0; o < COUT; ++o) yb[base + (size_t)o * EDG] = f2bf(acc[o]);
    } else {
#pragma unroll
        for (int o = 0; o < COUT; ++o) yf[base + (size_t)o * EDG] = acc[o];
    }
}

// per-channel sum / sumsq over (B,E)
template <bool WSY>
__global__ __launch_bounds__(256) void k_stats(const unsigned short* __restrict__ yb,
                                               const float* __restrict__ yf,
                                               float* __restrict__ stats) {
    int o = blockIdx.y;
    float s = 0.f, s2 = 0.f;
    if constexpr (WSY) {
        const int nvec = EDG / 8;  // 7500
        for (int i = blockIdx.x * 256 + threadIdx.x; i < BB * nvec; i += gridDim.x * 256) {
            int b = i / nvec, t = i - b * nvec;
            us8 v = reinterpret_cast<const us8*>(yb)[(size_t)(b * COUT + o) * nvec + t];
#pragma unroll
            for (int k = 0; k < 8; ++k) {
                float f = bf2f(v[k]);
                s += f;
                s2 = fmaf(f, f, s2);
            }
        }
    } else {
        const int nvec = EDG / 4;  // 15000
        for (int i = blockIdx.x * 256 + threadIdx.x; i < BB * nvec; i += gridDim.x * 256) {
            int b = i / nvec, t = i - b * nvec;
            float4 v = reinterpret_cast<const float4*>(yf)[(size_t)(b * COUT + o) * nvec + t];
            s += v.x + v.y + v.z + v.w;
            s2 = fmaf(v.x, v.x, s2);
            s2 = fmaf(v.y, v.y, s2);
            s2 = fmaf(v.z, v.z, s2);
            s2 = fmaf(v.w, v.w, s2);
        }
    }
#pragma unroll
    for (int off = 32; off; off >>= 1) {
        s += __shfl_down(s, off);
        s2 += __shfl_down(s2, off);
    }
    __shared__ float ls[4], ls2[4];
    int wid = threadIdx.x >> 6, lid = threadIdx.x & 63;
    if (lid == 0) { ls[wid] = s; ls2[wid] = s2; }
    __syncthreads();
    if (threadIdx.x == 0) {
        float t = 0.f, t2 = 0.f;
#pragma unroll
        for (int k = 0; k < 4; ++k) { t += ls[k]; t2 += ls2[k]; }
        atomicAdd(&stats[o], t);
        atomicAdd(&stats[COUT + o], t2);
    }
}

// BatchNorm (batch stats) + ReLU -> f32 output
template <bool WSY>
__global__ __launch_bounds__(256) void k_norm(const unsigned short* __restrict__ yb,
                                              float* __restrict__ yf,
                                              const float* __restrict__ stats,
                                              const float* __restrict__ gamma,
                                              const float* __restrict__ beta) {
    int i = blockIdx.x * 256 + threadIdx.x;  // one per 8 elements
    if (i >= YELEMS / 8) return;
    int row = (int)(((long long)i * 8) / EDG);  // b*COUT + o  (8 | EDG -> one row per vec)
    int o = row & (COUT - 1);
    const float inv_n = 1.0f / (float)NE;
    float mean = stats[o] * inv_n;
    float var = fmaf(-mean, mean, stats[COUT + o] * inv_n);
    float sc = gamma[o] * rsqrtf(var + EPS);
    float sh = fmaf(-mean, sc, beta[o]);

    float4 r0, r1;
    if constexpr (WSY) {
        us8 v = reinterpret_cast<const us8*>(yb)[i];
        float t[8];
#pragma unroll
        for (int k = 0; k < 8; ++k) t[k] = fmaxf(fmaf(bf2f(v[k]), sc, sh), 0.f);
        r0 = make_float4(t[0], t[1], t[2], t[3]);
        r1 = make_float4(t[4], t[5], t[6], t[7]);
    } else {
        float4 a = reinterpret_cast<float4*>(yf)[2 * i];
        float4 b = reinterpret_cast<float4*>(yf)[2 * i + 1];
        r0 = make_float4(fmaxf(fmaf(a.x, sc, sh), 0.f), fmaxf(fmaf(a.y, sc, sh), 0.f),
                         fmaxf(fmaf(a.z, sc, sh), 0.f), fmaxf(fmaf(a.w, sc, sh), 0.f));
        r1 = make_float4(fmaxf(fmaf(b.x, sc, sh), 0.f), fmaxf(fmaf(b.y, sc, sh), 0.f),
                         fmaxf(fmaf(b.z, sc, sh), 0.f), fmaxf(fmaf(b.w, sc, sh), 0.f));
    }
    reinterpret_cast<float4*>(yf)[2 * i] = r0;
    reinterpret_cast<float4*>(yf)[2 * i + 1] = r1;
}

extern "C" void kernel_launch(void* const* d_in, const int* in_sizes, int n_in,
                              void* d_out, int out_size, void* d_ws, size_t ws_size,
                              hipStream_t stream) {
    const float* x = (const float*)d_in[0];
    const int* gemm = (const int*)d_in[1];
    const float* w = (const float*)d_in[2];
    // d_in[3] = bias: cancels under BatchNorm, unused
    const float* gamma = (const float*)d_in[4];
    const float* beta = (const float*)d_in[5];

    float* yout = (float*)d_out;          // [B,COUT,E] f32
    float* gout = yout + YELEMS;          // [B,E,4] f32 mesh pass-through

    const size_t XT_BYTES = (size_t)NE * CIN * sizeof(unsigned short);   // 30.72 MB
    const size_t YB_BYTES = (size_t)YELEMS * sizeof(unsigned short);     // 61.44 MB

    unsigned short* xt = (unsigned short*)d_ws;
    bool wsy = ws_size >= XT_BYTES + YB_BYTES + 256;
    unsigned short* yb = (unsigned short*)((char*)d_ws + XT_BYTES);
    float* stats = (float*)((char*)d_ws + XT_BYTES + (wsy ? YB_BYTES : 0));

    hipMemsetAsync(stats, 0, 2 * COUT * sizeof(float), stream);
    k_transpose<<<NE / 256, 256, 0, stream>>>(x, xt);
    k_gemmcopy<<<GELEMS / 4 / 256, 256, 0, stream>>>(gemm, gout);
    if (wsy) {
        k_conv<true><<<NE / 256, 256, 0, stream>>>(xt, gemm, w, yb, yout);
        k_stats<true><<<dim3(60, COUT), 256, 0, stream>>>(yb, yout, stats);
        k_norm<true><<<YELEMS / 8 / 256, 256, 0, stream>>>(yb, yout, stats, gamma, beta);
    } else {
        k_conv<false><<<NE / 256, 256, 0, stream>>>(xt, gemm, w, yb, yout);
        k_stats<false><<<dim3(60, COUT), 256, 0, stream>>>(yb, yout, stats);
        k_norm<false><<<YELEMS / 8 / 256, 256, 0, stream>>>(yb, yout, stats, gamma, beta);
    }
}

// Round 3
// 193.853 us; speedup vs baseline: 1.0283x; 1.0283x over previous
//
#include <hip/hip_runtime.h>
#include <hip/hip_bf16.h>

#define BB 16
#define CIN 16
#define COUT 32
#define EDG 60000
#define NE (BB * EDG)            // 960000 edges
#define YELEMS (BB * COUT * EDG) // 30,720,000 f32 out elems for y
#define GELEMS (NE * 4)          // 3,840,000 f32 out elems for gemm
#define EPS 1e-5f
#define EBLKS 235                // ceil(60000/256)
#define KPAD 104                 // bf16 per LDS row (208 B, stride 52 dwords)
#define ROWB (KPAD * 2)          // 208 bytes

typedef unsigned short us8 __attribute__((ext_vector_type(8)));
typedef short s8v __attribute__((ext_vector_type(8)));   // 8 bf16 bit-patterns (4 VGPRs)
typedef float f32x4 __attribute__((ext_vector_type(4)));

// round-to-nearest-even f32 -> bf16 bits
static __device__ __forceinline__ unsigned short f2bf(float f) {
    unsigned u = __float_as_uint(f);
    return (unsigned short)((u + 0x7FFFu + ((u >> 16) & 1u)) >> 16);
}
static __device__ __forceinline__ float bf2f(unsigned short h) {
    return __uint_as_float(((unsigned)h) << 16);
}
static __device__ __forceinline__ float bf2fs(short h) {
    return __uint_as_float(((unsigned)(unsigned short)h) << 16);
}

// xt[b][e][c] = bf16(x[b][c][e])  -> each edge's 16 channels = one 32B row
__global__ __launch_bounds__(256) void k_transpose(const float* __restrict__ x,
                                                   unsigned short* __restrict__ xt) {
    int idx = blockIdx.x * 256 + threadIdx.x;
    if (idx >= NE) return;
    int b = idx / EDG, e = idx - b * EDG;
    const float* xp = x + (size_t)b * CIN * EDG + e;
    float v[CIN];
#pragma unroll
    for (int c = 0; c < CIN; ++c) v[c] = xp[(size_t)c * EDG];
    us8* o = reinterpret_cast<us8*>(xt + (size_t)idx * CIN);
#pragma unroll
    for (int h = 0; h < 2; ++h) {
        us8 r;
#pragma unroll
        for (int j = 0; j < 8; ++j) r[j] = f2bf(v[8 * h + j]);
        o[h] = r;
    }
}

// pass-through mesh: gemm int -> f32 in output tail (exact: indices < 2^24)
__global__ __launch_bounds__(256) void k_gemmcopy(const int* __restrict__ g,
                                                  float* __restrict__ og) {
    int i = blockIdx.x * 256 + threadIdx.x;
    if (i >= GELEMS / 4) return;
    int4 v = reinterpret_cast<const int4*>(g)[i];
    reinterpret_cast<float4*>(og)[i] =
        make_float4((float)v.x, (float)v.y, (float)v.z, (float)v.w);
}

// ---- MFMA mesh conv ----
// GEMM view: y[NE,32] = feats[NE,80] * w^T[80,32].  A = weights (M=COUT=32, 2 m-tiles),
// B = feats (N = 64 edges/wave, 4 n-tiles), K = 80 padded to 96 (3 k-tiles of 32).
// K-order is f-major: k = f*16 + c, so f0-block == raw self row and weight addr is
// w[o*80 + (k&15)*5 + (k>>4)].  Feats are staged per-wave in LDS [64][KPAD] bf16
// (stride 208B: 8 distinct bank-group starts => b128 throughput floor, no extra conflict).
// C/D layout (m89-verified): col=lane&15 -> edge (coalesced stores), row=(lane>>4)*4+reg -> o.
// bias skipped: per-channel constant cancels exactly under train-mode BatchNorm.
template <bool WSY>
__global__ __launch_bounds__(256) void k_conv(const unsigned short* __restrict__ xt,
                                              const int* __restrict__ gemm,
                                              const float* __restrict__ w,
                                              unsigned short* __restrict__ yb,
                                              float* __restrict__ yf) {
    __shared__ __align__(16) char lds[4 * 64 * ROWB];  // 53248 B

    // XCD pinning: batch bat -> XCD bat&7 (2 batches ~ 3.84MB xt rows per XCD L2)
    int bid = blockIdx.x;            // grid = 8 * 470
    int xcd = bid & 7, j = bid >> 3; // j in 0..469
    int bat = xcd + 8 * (j & 1);
    int eblk = j >> 1;               // 0..234
    int tid = threadIdx.x;
    int wid = tid >> 6, lane = tid & 63;
    int lo = lane & 15, hi = lane >> 4;
    int e0 = eblk * 256 + wid * 64;

    // ---- build A fragments (weights), once per wave ----
    s8v afrag[2][3];
#pragma unroll
    for (int mt = 0; mt < 2; ++mt) {
        int o = mt * 16 + lo;
#pragma unroll
        for (int kt = 0; kt < 3; ++kt) {
            s8v t;
#pragma unroll
            for (int jj = 0; jj < 8; ++jj) {
                int k = kt * 32 + hi * 8 + jj;
                float wv = (k < 80) ? w[o * 80 + (k & 15) * 5 + (k >> 4)] : 0.f;
                t[jj] = (short)f2bf(wv);
            }
            afrag[mt][kt] = t;
        }
    }

    // ---- gather + features -> LDS row ----
    int e = e0 + lane;
    int eld = e < EDG ? e : EDG - 1;
    int4 g4 = reinterpret_cast<const int4*>(gemm)[(size_t)bat * EDG + eld];
    const us8* xb = reinterpret_cast<const us8*>(xt) + (size_t)bat * EDG * 2;
    us8 s0 = xb[(size_t)eld * 2],  s1 = xb[(size_t)eld * 2 + 1];
    us8 a0 = xb[(size_t)g4.x * 2], a1 = xb[(size_t)g4.x * 2 + 1];
    us8 b0 = xb[(size_t)g4.y * 2], b1 = xb[(size_t)g4.y * 2 + 1];
    us8 c0 = xb[(size_t)g4.z * 2], c1 = xb[(size_t)g4.z * 2 + 1];
    us8 d0 = xb[(size_t)g4.w * 2], d1 = xb[(size_t)g4.w * 2 + 1];

    us8* rowv = reinterpret_cast<us8*>(lds + (size_t)(wid * 64 + lane) * ROWB);
    rowv[0] = s0;  // f0 block k0..7
    rowv[1] = s1;  // f0 block k8..15

    // f1=a+c, f2=|a-c|, f3=b+d, f4=|b-d| (computed f32, packed bf16)
    {
        us8 f1l, f1h, f2l, f2h, f3l, f3h, f4l, f4h;
#pragma unroll
        for (int i = 0; i < 8; ++i) {
            float pa = bf2f(a0[i]), qa = bf2f(c0[i]);
            f1l[i] = f2bf(pa + qa);
            f2l[i] = f2bf(fabsf(pa - qa));
            float pb = bf2f(a1[i]), qb = bf2f(c1[i]);
            f1h[i] = f2bf(pb + qb);
            f2h[i] = f2bf(fabsf(pb - qb));
            float pc = bf2f(b0[i]), qc = bf2f(d0[i]);
            f3l[i] = f2bf(pc + qc);
            f4l[i] = f2bf(fabsf(pc - qc));
            float pd = bf2f(b1[i]), qd = bf2f(d1[i]);
            f3h[i] = f2bf(pd + qd);
            f4h[i] = f2bf(fabsf(pd - qd));
        }
        us8 z = {0, 0, 0, 0, 0, 0, 0, 0};
        rowv[2] = f1l; rowv[3] = f1h;
        rowv[4] = f2l; rowv[5] = f2h;
        rowv[6] = f3l; rowv[7] = f3h;
        rowv[8] = f4l; rowv[9] = f4h;
        rowv[10] = z;  rowv[11] = z;   // k80..95 zero-pad (read by kt=2)
    }
    // LDS regions are per-wave private: same wave writes then reads its own 64 rows;
    // compiler inserts the lgkmcnt dependency waits, no __syncthreads needed.

    // ---- MFMA: 4 n-tiles x 3 k-tiles x 2 m-tiles ----
    f32x4 acc[2][4];
#pragma unroll
    for (int mt = 0; mt < 2; ++mt)
#pragma unroll
        for (int nt = 0; nt < 4; ++nt) acc[mt][nt] = (f32x4){0.f, 0.f, 0.f, 0.f};

    const char* wbase = lds + (size_t)wid * 64 * ROWB;
#pragma unroll
    for (int nt = 0; nt < 4; ++nt) {
        const char* rb = wbase + (size_t)(nt * 16 + lo) * ROWB + hi * 16;
        s8v bk0 = *reinterpret_cast<const s8v*>(rb);        // k 0..31 slice
        s8v bk1 = *reinterpret_cast<const s8v*>(rb + 64);   // k 32..63 slice
        s8v bk2 = *reinterpret_cast<const s8v*>(rb + 128);  // k 64..95 slice
#pragma unroll
        for (int mt = 0; mt < 2; ++mt) {
            acc[mt][nt] = __builtin_amdgcn_mfma_f32_16x16x32_bf16(afrag[mt][0], bk0, acc[mt][nt], 0, 0, 0);
            acc[mt][nt] = __builtin_amdgcn_mfma_f32_16x16x32_bf16(afrag[mt][1], bk1, acc[mt][nt], 0, 0, 0);
            acc[mt][nt] = __builtin_amdgcn_mfma_f32_16x16x32_bf16(afrag[mt][2], bk2, acc[mt][nt], 0, 0, 0);
        }
    }

    // ---- store: 16 consecutive edges per 16-lane group (coalesced) ----
    size_t ybase = (size_t)bat * COUT * EDG;
#pragma unroll
    for (int nt = 0; nt < 4; ++nt) {
        int ee = e0 + nt * 16 + lo;
        if (ee < EDG) {
#pragma unroll
            for (int mt = 0; mt < 2; ++mt)
#pragma unroll
                for (int r = 0; r < 4; ++r) {
                    int o = mt * 16 + hi * 4 + r;
                    if constexpr (WSY)
                        yb[ybase + (size_t)o * EDG + ee] = f2bf(acc[mt][nt][r]);
                    else
                        yf[ybase + (size_t)o * EDG + ee] = acc[mt][nt][r];
                }
        }
    }
}

// per-channel sum / sumsq over (B,E)
template <bool WSY>
__global__ __launch_bounds__(256) void k_stats(const unsigned short* __restrict__ yb,
                                               const float* __restrict__ yf,
                                               float* __restrict__ stats) {
    int o = blockIdx.y;
    float s = 0.f, s2 = 0.f;
    if constexpr (WSY) {
        const int nvec = EDG / 8;  // 7500
        for (int i = blockIdx.x * 256 + threadIdx.x; i < BB * nvec; i += gridDim.x * 256) {
            int b = i / nvec, t = i - b * nvec;
            us8 v = reinterpret_cast<const us8*>(yb)[(size_t)(b * COUT + o) * nvec + t];
#pragma unroll
            for (int k = 0; k < 8; ++k) {
                float f = bf2f(v[k]);
                s += f;
                s2 = fmaf(f, f, s2);
            }
        }
    } else {
        const int nvec = EDG / 4;  // 15000
        for (int i = blockIdx.x * 256 + threadIdx.x; i < BB * nvec; i += gridDim.x * 256) {
            int b = i / nvec, t = i - b * nvec;
            float4 v = reinterpret_cast<const float4*>(yf)[(size_t)(b * COUT + o) * nvec + t];
            s += v.x + v.y + v.z + v.w;
            s2 = fmaf(v.x, v.x, s2);
            s2 = fmaf(v.y, v.y, s2);
            s2 = fmaf(v.z, v.z, s2);
            s2 = fmaf(v.w, v.w, s2);
        }
    }
#pragma unroll
    for (int off = 32; off; off >>= 1) {
        s += __shfl_down(s, off);
        s2 += __shfl_down(s2, off);
    }
    __shared__ float ls[4], ls2[4];
    int wid = threadIdx.x >> 6, lid = threadIdx.x & 63;
    if (lid == 0) { ls[wid] = s; ls2[wid] = s2; }
    __syncthreads();
    if (threadIdx.x == 0) {
        float t = 0.f, t2 = 0.f;
#pragma unroll
        for (int k = 0; k < 4; ++k) { t += ls[k]; t2 += ls2[k]; }
        atomicAdd(&stats[o], t);
        atomicAdd(&stats[COUT + o], t2);
    }
}

// BatchNorm (batch stats) + ReLU -> f32 output
template <bool WSY>
__global__ __launch_bounds__(256) void k_norm(const unsigned short* __restrict__ yb,
                                              float* __restrict__ yf,
                                              const float* __restrict__ stats,
                                              const float* __restrict__ gamma,
                                              const float* __restrict__ beta) {
    int i = blockIdx.x * 256 + threadIdx.x;  // one per 8 elements
    if (i >= YELEMS / 8) return;
    int row = (int)(((long long)i * 8) / EDG);  // b*COUT + o
    int o = row & (COUT - 1);
    const float inv_n = 1.0f / (float)NE;
    float mean = stats[o] * inv_n;
    float var = fmaf(-mean, mean, stats[COUT + o] * inv_n);
    float sc = gamma[o] * rsqrtf(var + EPS);
    float sh = fmaf(-mean, sc, beta[o]);

    float4 r0, r1;
    if constexpr (WSY) {
        us8 v = reinterpret_cast<const us8*>(yb)[i];
        float t[8];
#pragma unroll
        for (int k = 0; k < 8; ++k) t[k] = fmaxf(fmaf(bf2f(v[k]), sc, sh), 0.f);
        r0 = make_float4(t[0], t[1], t[2], t[3]);
        r1 = make_float4(t[4], t[5], t[6], t[7]);
    } else {
        float4 a = reinterpret_cast<float4*>(yf)[2 * i];
        float4 b = reinterpret_cast<float4*>(yf)[2 * i + 1];
        r0 = make_float4(fmaxf(fmaf(a.x, sc, sh), 0.f), fmaxf(fmaf(a.y, sc, sh), 0.f),
                         fmaxf(fmaf(a.z, sc, sh), 0.f), fmaxf(fmaf(a.w, sc, sh), 0.f));
        r1 = make_float4(fmaxf(fmaf(b.x, sc, sh), 0.f), fmaxf(fmaf(b.y, sc, sh), 0.f),
                         fmaxf(fmaf(b.z, sc, sh), 0.f), fmaxf(fmaf(b.w, sc, sh), 0.f));
    }
    reinterpret_cast<float4*>(yf)[2 * i] = r0;
    reinterpret_cast<float4*>(yf)[2 * i + 1] = r1;
}

extern "C" void kernel_launch(void* const* d_in, const int* in_sizes, int n_in,
                              void* d_out, int out_size, void* d_ws, size_t ws_size,
                              hipStream_t stream) {
    const float* x = (const float*)d_in[0];
    const int* gemm = (const int*)d_in[1];
    const float* w = (const float*)d_in[2];
    // d_in[3] = bias: cancels under BatchNorm, unused
    const float* gamma = (const float*)d_in[4];
    const float* beta = (const float*)d_in[5];

    float* yout = (float*)d_out;          // [B,COUT,E] f32
    float* gout = yout + YELEMS;          // [B,E,4] f32 mesh pass-through

    const size_t XT_BYTES = (size_t)NE * CIN * sizeof(unsigned short);   // 30.72 MB
    const size_t YB_BYTES = (size_t)YELEMS * sizeof(unsigned short);     // 61.44 MB

    unsigned short* xt = (unsigned short*)d_ws;
    bool wsy = ws_size >= XT_BYTES + YB_BYTES + 256;
    unsigned short* yb = (unsigned short*)((char*)d_ws + XT_BYTES);
    float* stats = (float*)((char*)d_ws + XT_BYTES + (wsy ? YB_BYTES : 0));

    hipMemsetAsync(stats, 0, 2 * COUT * sizeof(float), stream);
    k_transpose<<<NE / 256, 256, 0, stream>>>(x, xt);
    k_gemmcopy<<<GELEMS / 4 / 256, 256, 0, stream>>>(gemm, gout);
    if (wsy) {
        k_conv<true><<<8 * 2 * EBLKS, 256, 0, stream>>>(xt, gemm, w, yb, yout);
        k_stats<true><<<dim3(60, COUT), 256, 0, stream>>>(yb, yout, stats);
        k_norm<true><<<YELEMS / 8 / 256, 256, 0, stream>>>(yb, yout, stats, gamma, beta);
    } else {
        k_conv<false><<<8 * 2 * EBLKS, 256, 0, stream>>>(xt, gemm, w, yb, yout);
        k_stats<false><<<dim3(60, COUT), 256, 0, stream>>>(yb, yout, stats);
        k_norm<false><<<YELEMS / 8 / 256, 256, 0, stream>>>(yb, yout, stats, gamma, beta);
    }
}

// Round 4
// 149.885 us; speedup vs baseline: 1.3299x; 1.2933x over previous
//
#include <hip/hip_runtime.h>
#include <hip/hip_bf16.h>

#define BB 16
#define CIN 16
#define COUT 32
#define EDG 60000
#define NE (BB * EDG)            // 960000 edges
#define YELEMS (BB * COUT * EDG) // 30,720,000 f32 out elems for y
#define GELEMS (NE * 4)          // 3,840,000 f32 out elems for gemm
#define EPS 1e-5f
#define EBLKS 235                // ceil(60000/256)
#define KPAD 104                 // bf16 per LDS feat row (208 B)
#define ROWB (KPAD * 2)          // 208 bytes
#define TPAD 36                  // f32 per transpose row (144 B, 16B-aligned)

typedef unsigned short us8 __attribute__((ext_vector_type(8)));
typedef short s8v __attribute__((ext_vector_type(8)));   // 8 bf16 bit-patterns (4 VGPRs)
typedef float f32x4 __attribute__((ext_vector_type(4)));

// round-to-nearest-even f32 -> bf16 bits
static __device__ __forceinline__ unsigned short f2bf(float f) {
    unsigned u = __float_as_uint(f);
    return (unsigned short)((u + 0x7FFFu + ((u >> 16) & 1u)) >> 16);
}
static __device__ __forceinline__ float bf2f(unsigned short h) {
    return __uint_as_float(((unsigned)h) << 16);
}

// xt[b][e][c] = bf16(x[b][c][e])  -> each edge's 16 channels = one 32B row
__global__ __launch_bounds__(256) void k_transpose(const float* __restrict__ x,
                                                   unsigned short* __restrict__ xt) {
    int idx = blockIdx.x * 256 + threadIdx.x;
    if (idx >= NE) return;
    int b = idx / EDG, e = idx - b * EDG;
    const float* xp = x + (size_t)b * CIN * EDG + e;
    float v[CIN];
#pragma unroll
    for (int c = 0; c < CIN; ++c) v[c] = xp[(size_t)c * EDG];
    us8* o = reinterpret_cast<us8*>(xt + (size_t)idx * CIN);
#pragma unroll
    for (int h = 0; h < 2; ++h) {
        us8 r;
#pragma unroll
        for (int j = 0; j < 8; ++j) r[j] = f2bf(v[8 * h + j]);
        o[h] = r;
    }
}

// pass-through mesh: gemm int -> f32 in output tail (exact: indices < 2^24)
__global__ __launch_bounds__(256) void k_gemmcopy(const int* __restrict__ g,
                                                  float* __restrict__ og) {
    int i = blockIdx.x * 256 + threadIdx.x;
    if (i >= GELEMS / 4) return;
    int4 v = reinterpret_cast<const int4*>(g)[i];
    reinterpret_cast<float4*>(og)[i] =
        make_float4((float)v.x, (float)v.y, (float)v.z, (float)v.w);
}

// Build per-lane MFMA A-fragments (weights) ONCE. Layout afragG[(mt*3+kt)*64+lane].
// k-order is f-major: k = f*16 + c  ->  w[o*80 + (k&15)*5 + (k>>4)], zero for k>=80.
__global__ __launch_bounds__(64) void k_wprep(const float* __restrict__ w,
                                              s8v* __restrict__ afragG) {
    int lane = threadIdx.x;
    int lo = lane & 15, hi = lane >> 4;
#pragma unroll
    for (int mt = 0; mt < 2; ++mt) {
        int o = mt * 16 + lo;
#pragma unroll
        for (int kt = 0; kt < 3; ++kt) {
            s8v t;
#pragma unroll
            for (int jj = 0; jj < 8; ++jj) {
                int k = kt * 32 + hi * 8 + jj;
                float wv = (k < 80) ? w[o * 80 + (k & 15) * 5 + (k >> 4)] : 0.f;
                t[jj] = (short)f2bf(wv);
            }
            afragG[(mt * 3 + kt) * 64 + lane] = t;
        }
    }
}

// ---- MFMA mesh conv ----
// GEMM view: y[NE,32] = feats[NE,80] * w^T[80,32].  A = weights (2 m-tiles of 16),
// B = feats (4 n-tiles of 16 edges), K = 80 padded to 96 (3 k-tiles of 32).
// Feats staged per-wave in LDS [64][KPAD] bf16; epilogue transposes acc via the same
// LDS region ([64][TPAD] f32) so each lane owns one o-row -> 4 us8 (16B) stores.
// bias skipped: per-channel constant cancels exactly under train-mode BatchNorm.
template <bool WSY>
__global__ __launch_bounds__(256) void k_conv(const unsigned short* __restrict__ xt,
                                              const int* __restrict__ gemm,
                                              const s8v* __restrict__ afragG,
                                              unsigned short* __restrict__ yb,
                                              float* __restrict__ yf) {
    __shared__ __align__(16) char lds[4 * 64 * ROWB];  // 53248 B

    // XCD pinning: batch bat -> XCD bat&7 (2 batches ~ 3.84MB xt rows per XCD L2)
    int bid = blockIdx.x;            // grid = 8 * 470
    int xcd = bid & 7, j = bid >> 3; // j in 0..469
    int bat = xcd + 8 * (j & 1);
    int eblk = j >> 1;               // 0..234
    int tid = threadIdx.x;
    int wid = tid >> 6, lane = tid & 63;
    int lo = lane & 15, hi = lane >> 4;
    int e0 = eblk * 256 + wid * 64;

    // ---- A fragments: 6 coalesced b128 loads (L1-resident, 6KB shared) ----
    s8v afrag[2][3];
#pragma unroll
    for (int mt = 0; mt < 2; ++mt)
#pragma unroll
        for (int kt = 0; kt < 3; ++kt)
            afrag[mt][kt] = afragG[(mt * 3 + kt) * 64 + lane];

    // ---- gather + features -> LDS row ----
    int e = e0 + lane;
    int eld = e < EDG ? e : EDG - 1;
    int4 g4 = reinterpret_cast<const int4*>(gemm)[(size_t)bat * EDG + eld];
    const us8* xb = reinterpret_cast<const us8*>(xt) + (size_t)bat * EDG * 2;
    us8 s0 = xb[(size_t)eld * 2],  s1 = xb[(size_t)eld * 2 + 1];
    us8 a0 = xb[(size_t)g4.x * 2], a1 = xb[(size_t)g4.x * 2 + 1];
    us8 b0 = xb[(size_t)g4.y * 2], b1 = xb[(size_t)g4.y * 2 + 1];
    us8 c0 = xb[(size_t)g4.z * 2], c1 = xb[(size_t)g4.z * 2 + 1];
    us8 d0 = xb[(size_t)g4.w * 2], d1 = xb[(size_t)g4.w * 2 + 1];

    us8* rowv = reinterpret_cast<us8*>(lds + (size_t)(wid * 64 + lane) * ROWB);
    rowv[0] = s0;  // f0 block k0..7
    rowv[1] = s1;  // f0 block k8..15
    {
        us8 f1l, f1h, f2l, f2h, f3l, f3h, f4l, f4h;
#pragma unroll
        for (int i = 0; i < 8; ++i) {
            float pa = bf2f(a0[i]), qa = bf2f(c0[i]);
            f1l[i] = f2bf(pa + qa);
            f2l[i] = f2bf(fabsf(pa - qa));
            float pb = bf2f(a1[i]), qb = bf2f(c1[i]);
            f1h[i] = f2bf(pb + qb);
            f2h[i] = f2bf(fabsf(pb - qb));
            float pc = bf2f(b0[i]), qc = bf2f(d0[i]);
            f3l[i] = f2bf(pc + qc);
            f4l[i] = f2bf(fabsf(pc - qc));
            float pd = bf2f(b1[i]), qd = bf2f(d1[i]);
            f3h[i] = f2bf(pd + qd);
            f4h[i] = f2bf(fabsf(pd - qd));
        }
        us8 z = {0, 0, 0, 0, 0, 0, 0, 0};
        rowv[2] = f1l; rowv[3] = f1h;
        rowv[4] = f2l; rowv[5] = f2h;
        rowv[6] = f3l; rowv[7] = f3h;
        rowv[8] = f4l; rowv[9] = f4h;
        rowv[10] = z;  rowv[11] = z;   // k80..95 zero-pad (read by kt=2)
    }
    // wave-private LDS region: same wave writes then reads; lgkmcnt deps suffice.

    // ---- MFMA: 4 n-tiles x 3 k-tiles x 2 m-tiles ----
    f32x4 acc[2][4];
#pragma unroll
    for (int mt = 0; mt < 2; ++mt)
#pragma unroll
        for (int nt = 0; nt < 4; ++nt) acc[mt][nt] = (f32x4){0.f, 0.f, 0.f, 0.f};

    const char* wbase = lds + (size_t)wid * 64 * ROWB;
#pragma unroll
    for (int nt = 0; nt < 4; ++nt) {
        const char* rb = wbase + (size_t)(nt * 16 + lo) * ROWB + hi * 16;
        s8v bk0 = *reinterpret_cast<const s8v*>(rb);        // k 0..31
        s8v bk1 = *reinterpret_cast<const s8v*>(rb + 64);   // k 32..63
        s8v bk2 = *reinterpret_cast<const s8v*>(rb + 128);  // k 64..95
#pragma unroll
        for (int mt = 0; mt < 2; ++mt) {
            acc[mt][nt] = __builtin_amdgcn_mfma_f32_16x16x32_bf16(afrag[mt][0], bk0, acc[mt][nt], 0, 0, 0);
            acc[mt][nt] = __builtin_amdgcn_mfma_f32_16x16x32_bf16(afrag[mt][1], bk1, acc[mt][nt], 0, 0, 0);
            acc[mt][nt] = __builtin_amdgcn_mfma_f32_16x16x32_bf16(afrag[mt][2], bk2, acc[mt][nt], 0, 0, 0);
        }
    }

    // ---- epilogue: LDS transpose (reuse feat region) -> per-lane o-row stores ----
    // C/D layout (m89-verified): col=lane&15 -> edge, row=(lane>>4)*4+reg -> o.
    float* trow = reinterpret_cast<float*>(lds + (size_t)wid * 64 * ROWB);  // [64][TPAD] f32
#pragma unroll
    for (int mt = 0; mt < 2; ++mt)
#pragma unroll
        for (int nt = 0; nt < 4; ++nt) {
            int e_loc = nt * 16 + lo, o_s = mt * 16 + hi * 4;
            *reinterpret_cast<f32x4*>(trow + e_loc * TPAD + o_s) = acc[mt][nt];
        }

    int oo = lane >> 1, eh = lane & 1;            // lane owns o-row oo, edge half eh
    size_t obase = (size_t)bat * COUT * EDG + (size_t)oo * EDG + e0 + eh * 32;
    const float* rr = trow + oo;
#pragma unroll
    for (int q = 0; q < 4; ++q) {
        int eg = e0 + eh * 32 + q * 8;
        if (eg < EDG) {                            // EDG % 8 == 0 -> 8-granular guard exact
            if constexpr (WSY) {
                us8 pk;
#pragma unroll
                for (int jj = 0; jj < 8; ++jj)
                    pk[jj] = f2bf(rr[(eh * 32 + q * 8 + jj) * TPAD]);
                *reinterpret_cast<us8*>(yb + obase + q * 8) = pk;
            } else {
                f32x4 pk0, pk1;
#pragma unroll
                for (int jj = 0; jj < 4; ++jj) {
                    pk0[jj] = rr[(eh * 32 + q * 8 + jj) * TPAD];
                    pk1[jj] = rr[(eh * 32 + q * 8 + 4 + jj) * TPAD];
                }
                *reinterpret_cast<f32x4*>(yf + obase + q * 8) = pk0;
                *reinterpret_cast<f32x4*>(yf + obase + q * 8 + 4) = pk1;
            }
        }
    }
}

// per-channel sum / sumsq over (B,E)
template <bool WSY>
__global__ __launch_bounds__(256) void k_stats(const unsigned short* __restrict__ yb,
                                               const float* __restrict__ yf,
                                               float* __restrict__ stats) {
    int o = blockIdx.y;
    float s = 0.f, s2 = 0.f;
    if constexpr (WSY) {
        const int nvec = EDG / 8;  // 7500
        for (int i = blockIdx.x * 256 + threadIdx.x; i < BB * nvec; i += gridDim.x * 256) {
            int b = i / nvec, t = i - b * nvec;
            us8 v = reinterpret_cast<const us8*>(yb)[(size_t)(b * COUT + o) * nvec + t];
#pragma unroll
            for (int k = 0; k < 8; ++k) {
                float f = bf2f(v[k]);
                s += f;
                s2 = fmaf(f, f, s2);
            }
        }
    } else {
        const int nvec = EDG / 4;  // 15000
        for (int i = blockIdx.x * 256 + threadIdx.x; i < BB * nvec; i += gridDim.x * 256) {
            int b = i / nvec, t = i - b * nvec;
            float4 v = reinterpret_cast<const float4*>(yf)[(size_t)(b * COUT + o) * nvec + t];
            s += v.x + v.y + v.z + v.w;
            s2 = fmaf(v.x, v.x, s2);
            s2 = fmaf(v.y, v.y, s2);
            s2 = fmaf(v.z, v.z, s2);
            s2 = fmaf(v.w, v.w, s2);
        }
    }
#pragma unroll
    for (int off = 32; off; off >>= 1) {
        s += __shfl_down(s, off);
        s2 += __shfl_down(s2, off);
    }
    __shared__ float ls[4], ls2[4];
    int wid = threadIdx.x >> 6, lid = threadIdx.x & 63;
    if (lid == 0) { ls[wid] = s; ls2[wid] = s2; }
    __syncthreads();
    if (threadIdx.x == 0) {
        float t = 0.f, t2 = 0.f;
#pragma unroll
        for (int k = 0; k < 4; ++k) { t += ls[k]; t2 += ls2[k]; }
        atomicAdd(&stats[o], t);
        atomicAdd(&stats[COUT + o], t2);
    }
}

// BatchNorm (batch stats) + ReLU -> f32 output
template <bool WSY>
__global__ __launch_bounds__(256) void k_norm(const unsigned short* __restrict__ yb,
                                              float* __restrict__ yf,
                                              const float* __restrict__ stats,
                                              const float* __restrict__ gamma,
                                              const float* __restrict__ beta) {
    int i = blockIdx.x * 256 + threadIdx.x;  // one per 8 elements
    if (i >= YELEMS / 8) return;
    int row = (int)(((long long)i * 8) / EDG);  // b*COUT + o
    int o = row & (COUT - 1);
    const float inv_n = 1.0f / (float)NE;
    float mean = stats[o] * inv_n;
    float var = fmaf(-mean, mean, stats[COUT + o] * inv_n);
    float sc = gamma[o] * rsqrtf(var + EPS);
    float sh = fmaf(-mean, sc, beta[o]);

    float4 r0, r1;
    if constexpr (WSY) {
        us8 v = reinterpret_cast<const us8*>(yb)[i];
        float t[8];
#pragma unroll
        for (int k = 0; k < 8; ++k) t[k] = fmaxf(fmaf(bf2f(v[k]), sc, sh), 0.f);
        r0 = make_float4(t[0], t[1], t[2], t[3]);
        r1 = make_float4(t[4], t[5], t[6], t[7]);
    } else {
        float4 a = reinterpret_cast<float4*>(yf)[2 * i];
        float4 b = reinterpret_cast<float4*>(yf)[2 * i + 1];
        r0 = make_float4(fmaxf(fmaf(a.x, sc, sh), 0.f), fmaxf(fmaf(a.y, sc, sh), 0.f),
                         fmaxf(fmaf(a.z, sc, sh), 0.f), fmaxf(fmaf(a.w, sc, sh), 0.f));
        r1 = make_float4(fmaxf(fmaf(b.x, sc, sh), 0.f), fmaxf(fmaf(b.y, sc, sh), 0.f),
                         fmaxf(fmaf(b.z, sc, sh), 0.f), fmaxf(fmaf(b.w, sc, sh), 0.f));
    }
    reinterpret_cast<float4*>(yf)[2 * i] = r0;
    reinterpret_cast<float4*>(yf)[2 * i + 1] = r1;
}

extern "C" void kernel_launch(void* const* d_in, const int* in_sizes, int n_in,
                              void* d_out, int out_size, void* d_ws, size_t ws_size,
                              hipStream_t stream) {
    const float* x = (const float*)d_in[0];
    const int* gemm = (const int*)d_in[1];
    const float* w = (const float*)d_in[2];
    // d_in[3] = bias: cancels under BatchNorm, unused
    const float* gamma = (const float*)d_in[4];
    const float* beta = (const float*)d_in[5];

    float* yout = (float*)d_out;          // [B,COUT,E] f32
    float* gout = yout + YELEMS;          // [B,E,4] f32 mesh pass-through

    const size_t XT_BYTES = (size_t)NE * CIN * sizeof(unsigned short);   // 30.72 MB
    const size_t YB_BYTES = (size_t)YELEMS * sizeof(unsigned short);     // 61.44 MB

    unsigned short* xt = (unsigned short*)d_ws;
    bool wsy = ws_size >= XT_BYTES + YB_BYTES + 16384;
    char* tail = (char*)d_ws + XT_BYTES + (wsy ? YB_BYTES : 0);
    float* stats = (float*)tail;                      // 256 B
    s8v* afragG = (s8v*)(tail + 1024);                // 6144 B

    hipMemsetAsync(stats, 0, 2 * COUT * sizeof(float), stream);
    k_transpose<<<NE / 256, 256, 0, stream>>>(x, xt);
    k_gemmcopy<<<GELEMS / 4 / 256, 256, 0, stream>>>(gemm, gout);
    k_wprep<<<1, 64, 0, stream>>>(w, afragG);
    unsigned short* yb = (unsigned short*)((char*)d_ws + XT_BYTES);
    if (wsy) {
        k_conv<true><<<8 * 2 * EBLKS, 256, 0, stream>>>(xt, gemm, afragG, yb, yout);
        k_stats<true><<<dim3(60, COUT), 256, 0, stream>>>(yb, yout, stats);
        k_norm<true><<<YELEMS / 8 / 256, 256, 0, stream>>>(yb, yout, stats, gamma, beta);
    } else {
        k_conv<false><<<8 * 2 * EBLKS, 256, 0, stream>>>(xt, gemm, afragG, yb, yout);
        k_stats<false><<<dim3(60, COUT), 256, 0, stream>>>(yb, yout, stats);
        k_norm<false><<<YELEMS / 8 / 256, 256, 0, stream>>>(yb, yout, stats, gamma, beta);
    }
}

// Round 5
// 119.691 us; speedup vs baseline: 1.6655x; 1.2523x over previous
//
#include <hip/hip_runtime.h>
#include <hip/hip_bf16.h>

#define BB 16
#define CIN 16
#define COUT 32
#define EDG 60000
#define NE (BB * EDG)            // 960000 edges
#define YELEMS (BB * COUT * EDG) // 30,720,000 f32 out elems for y
#define GELEMS (NE * 4)          // 3,840,000 f32 out elems for gemm
#define EPS 1e-5f
#define EBLKS 235                // ceil(60000/256)
#define KPAD 104                 // bf16 per LDS feat row (208 B)
#define ROWB (KPAD * 2)          // 208 bytes
#define TPAD 36                  // f32 per transpose row
#define NREP 16                  // stats atomic replicas

typedef unsigned short us8 __attribute__((ext_vector_type(8)));
typedef short s8v __attribute__((ext_vector_type(8)));   // 8 bf16 bit-patterns
typedef float f32x4 __attribute__((ext_vector_type(4)));

static __device__ __forceinline__ unsigned short f2bf(float f) {
    unsigned u = __float_as_uint(f);
    return (unsigned short)((u + 0x7FFFu + ((u >> 16) & 1u)) >> 16);
}
static __device__ __forceinline__ float bf2f(unsigned short h) {
    return __uint_as_float(((unsigned)h) << 16);
}

// xt[b][e][c] = bf16(x[b][c][e])
__global__ __launch_bounds__(256) void k_transpose(const float* __restrict__ x,
                                                   unsigned short* __restrict__ xt) {
    int idx = blockIdx.x * 256 + threadIdx.x;
    if (idx >= NE) return;
    int b = idx / EDG, e = idx - b * EDG;
    const float* xp = x + (size_t)b * CIN * EDG + e;
    float v[CIN];
#pragma unroll
    for (int c = 0; c < CIN; ++c) v[c] = xp[(size_t)c * EDG];
    us8* o = reinterpret_cast<us8*>(xt + (size_t)idx * CIN);
#pragma unroll
    for (int h = 0; h < 2; ++h) {
        us8 r;
#pragma unroll
        for (int j = 0; j < 8; ++j) r[j] = f2bf(v[8 * h + j]);
        o[h] = r;
    }
}

// Build per-lane MFMA A-fragments once + zero the stats replicas.
// k-order f-major: k = f*16 + c -> w[o*80 + (k&15)*5 + (k>>4)], zero for k>=80.
__global__ __launch_bounds__(64) void k_wprep(const float* __restrict__ w,
                                              s8v* __restrict__ afragG,
                                              float* __restrict__ statsR) {
    int lane = threadIdx.x;
    int lo = lane & 15, hi = lane >> 4;
#pragma unroll
    for (int r = 0; r < NREP; ++r) statsR[r * 64 + lane] = 0.f;
#pragma unroll
    for (int mt = 0; mt < 2; ++mt) {
        int o = mt * 16 + lo;
#pragma unroll
        for (int kt = 0; kt < 3; ++kt) {
            s8v t;
#pragma unroll
            for (int jj = 0; jj < 8; ++jj) {
                int k = kt * 32 + hi * 8 + jj;
                float wv = (k < 80) ? w[o * 80 + (k & 15) * 5 + (k >> 4)] : 0.f;
                t[jj] = (short)f2bf(wv);
            }
            afragG[(mt * 3 + kt) * 64 + lane] = t;
        }
    }
}

struct Gath { us8 s0, s1, a0, a1, b0, b1, c0, c1, d0, d1; };

static __device__ __forceinline__ Gath gather10(const us8* __restrict__ xb, int eld, int4 g4) {
    Gath G;
    G.s0 = xb[(size_t)eld * 2];  G.s1 = xb[(size_t)eld * 2 + 1];
    G.a0 = xb[(size_t)g4.x * 2]; G.a1 = xb[(size_t)g4.x * 2 + 1];
    G.b0 = xb[(size_t)g4.y * 2]; G.b1 = xb[(size_t)g4.y * 2 + 1];
    G.c0 = xb[(size_t)g4.z * 2]; G.c1 = xb[(size_t)g4.z * 2 + 1];
    G.d0 = xb[(size_t)g4.w * 2]; G.d1 = xb[(size_t)g4.w * 2 + 1];
    return G;
}

static __device__ __forceinline__ void feats_to_lds(const Gath& G, us8* rowv) {
    rowv[0] = G.s0;  // f0 block k0..15
    rowv[1] = G.s1;
    us8 f1l, f1h, f2l, f2h, f3l, f3h, f4l, f4h;
#pragma unroll
    for (int i = 0; i < 8; ++i) {
        float pa = bf2f(G.a0[i]), qa = bf2f(G.c0[i]);
        f1l[i] = f2bf(pa + qa);
        f2l[i] = f2bf(fabsf(pa - qa));
        float pb = bf2f(G.a1[i]), qb = bf2f(G.c1[i]);
        f1h[i] = f2bf(pb + qb);
        f2h[i] = f2bf(fabsf(pb - qb));
        float pc = bf2f(G.b0[i]), qc = bf2f(G.d0[i]);
        f3l[i] = f2bf(pc + qc);
        f4l[i] = f2bf(fabsf(pc - qc));
        float pd = bf2f(G.b1[i]), qd = bf2f(G.d1[i]);
        f3h[i] = f2bf(pd + qd);
        f4h[i] = f2bf(fabsf(pd - qd));
    }
    us8 z = {0, 0, 0, 0, 0, 0, 0, 0};
    rowv[2] = f1l; rowv[3] = f1h;
    rowv[4] = f2l; rowv[5] = f2h;
    rowv[6] = f3l; rowv[7] = f3h;
    rowv[8] = f4l; rowv[9] = f4h;
    rowv[10] = z;  rowv[11] = z;   // k80..95 zero-pad
}

static __device__ __forceinline__ void mfma_all(const char* wbase, int lo, int hi,
                                                const s8v afrag[2][3], f32x4 acc[2][4]) {
#pragma unroll
    for (int mt = 0; mt < 2; ++mt)
#pragma unroll
        for (int nt = 0; nt < 4; ++nt) acc[mt][nt] = (f32x4){0.f, 0.f, 0.f, 0.f};
#pragma unroll
    for (int nt = 0; nt < 4; ++nt) {
        const char* rb = wbase + (size_t)(nt * 16 + lo) * ROWB + hi * 16;
        s8v bk0 = *reinterpret_cast<const s8v*>(rb);
        s8v bk1 = *reinterpret_cast<const s8v*>(rb + 64);
        s8v bk2 = *reinterpret_cast<const s8v*>(rb + 128);
#pragma unroll
        for (int mt = 0; mt < 2; ++mt) {
            acc[mt][nt] = __builtin_amdgcn_mfma_f32_16x16x32_bf16(afrag[mt][0], bk0, acc[mt][nt], 0, 0, 0);
            acc[mt][nt] = __builtin_amdgcn_mfma_f32_16x16x32_bf16(afrag[mt][1], bk1, acc[mt][nt], 0, 0, 0);
            acc[mt][nt] = __builtin_amdgcn_mfma_f32_16x16x32_bf16(afrag[mt][2], bk2, acc[mt][nt], 0, 0, 0);
        }
    }
}

// stats reduce + LDS transpose + coalesced y stores.
// C/D layout (m89-verified): col=lane&15 -> edge, row=(lane>>4)*4+reg -> o.
template <bool WSY>
static __device__ __forceinline__ void epilogue(const f32x4 acc[2][4], int bat, int e0,
                                                int wid, int lane, int lo, int hi,
                                                char* lds, unsigned short* __restrict__ yb,
                                                float* __restrict__ yf,
                                                float (*sacc)[COUT]) {
    // ---- per-channel sum/sumsq (f32 acc; valid nt-tiles only, 16-granular) ----
#pragma unroll
    for (int mt = 0; mt < 2; ++mt)
#pragma unroll
        for (int r = 0; r < 4; ++r) {
            float s = 0.f, q = 0.f;
#pragma unroll
            for (int nt = 0; nt < 4; ++nt)
                if (e0 + nt * 16 < EDG) {
                    float v = acc[mt][nt][r];
                    s += v;
                    q = fmaf(v, v, q);
                }
#pragma unroll
            for (int m = 1; m < 16; m <<= 1) {
                s += __shfl_xor(s, m);
                q += __shfl_xor(q, m);
            }
            if (lo == 0) {
                int o = mt * 16 + hi * 4 + r;
                atomicAdd(&sacc[0][o], s);
                atomicAdd(&sacc[1][o], q);
            }
        }

    // ---- LDS transpose (reuse feat region) -> per-lane o-row stores ----
    float* trow = reinterpret_cast<float*>(lds + (size_t)wid * 64 * ROWB);
#pragma unroll
    for (int mt = 0; mt < 2; ++mt)
#pragma unroll
        for (int nt = 0; nt < 4; ++nt) {
            int e_loc = nt * 16 + lo, o_s = mt * 16 + hi * 4;
            *reinterpret_cast<f32x4*>(trow + e_loc * TPAD + o_s) = acc[mt][nt];
        }

    int oo = lane >> 1, eh = lane & 1;
    size_t obase = (size_t)bat * COUT * EDG + (size_t)oo * EDG + e0 + eh * 32;
    const float* rr = trow + oo;
#pragma unroll
    for (int q = 0; q < 4; ++q) {
        int eg = e0 + eh * 32 + q * 8;
        if (eg < EDG) {   // EDG % 8 == 0 -> exact
            if constexpr (WSY) {
                us8 pk;
#pragma unroll
                for (int jj = 0; jj < 8; ++jj)
                    pk[jj] = f2bf(rr[(eh * 32 + q * 8 + jj) * TPAD]);
                *reinterpret_cast<us8*>(yb + obase + q * 8) = pk;
            } else {
                f32x4 pk0, pk1;
#pragma unroll
                for (int jj = 0; jj < 4; ++jj) {
                    pk0[jj] = rr[(eh * 32 + q * 8 + jj) * TPAD];
                    pk1[jj] = rr[(eh * 32 + q * 8 + 4 + jj) * TPAD];
                }
                *reinterpret_cast<f32x4*>(yf + obase + q * 8) = pk0;
                *reinterpret_cast<f32x4*>(yf + obase + q * 8 + 4) = pk1;
            }
        }
    }
}

// ---- fused MFMA mesh conv: gemm pass-through + conv + stats, 2 batches/block ----
template <bool WSY>
__global__ __launch_bounds__(256, 3) void k_conv(const unsigned short* __restrict__ xt,
                                                 const int* __restrict__ gemm,
                                                 const s8v* __restrict__ afragG,
                                                 unsigned short* __restrict__ yb,
                                                 float* __restrict__ yf,
                                                 float* __restrict__ gout,
                                                 float* __restrict__ statsR) {
    __shared__ __align__(16) char lds[4 * 64 * ROWB];  // 53248 B
    __shared__ float sacc[2][COUT];

    int bid = blockIdx.x;            // grid = 8 * EBLKS
    int xcd = bid & 7, eblk = bid >> 3;
    int bat0 = xcd, bat1 = xcd + 8;  // both pinned to XCD bid&7
    int tid = threadIdx.x;
    int wid = tid >> 6, lane = tid & 63;
    int lo = lane & 15, hi = lane >> 4;
    int e0 = eblk * 256 + wid * 64;
    int e = e0 + lane;
    int eld = min(e, EDG - 1);
    bool ev = e < EDG;

    if (tid < 64) sacc[tid >> 5][tid & 31] = 0.f;
    __syncthreads();

    // A fragments: 6 coalesced b128 loads (L1-resident)
    s8v afrag[2][3];
#pragma unroll
    for (int mt = 0; mt < 2; ++mt)
#pragma unroll
        for (int kt = 0; kt < 3; ++kt)
            afrag[mt][kt] = afragG[(mt * 3 + kt) * 64 + lane];

    const int4* gm = reinterpret_cast<const int4*>(gemm);
    int4 g4  = gm[(size_t)bat0 * EDG + eld];
    int4 g4n = gm[(size_t)bat1 * EDG + eld];

    // fused gemm pass-through (int->f32 exact, coalesced 16B stores)
    if (ev) {
        *reinterpret_cast<float4*>(gout + ((size_t)bat0 * EDG + e) * 4) =
            make_float4((float)g4.x, (float)g4.y, (float)g4.z, (float)g4.w);
        *reinterpret_cast<float4*>(gout + ((size_t)bat1 * EDG + e) * 4) =
            make_float4((float)g4n.x, (float)g4n.y, (float)g4n.z, (float)g4n.w);
    }

    const us8* xb0 = reinterpret_cast<const us8*>(xt) + (size_t)bat0 * EDG * 2;
    const us8* xb1 = reinterpret_cast<const us8*>(xt) + (size_t)bat1 * EDG * 2;
    us8* rowv = reinterpret_cast<us8*>(lds + (size_t)(wid * 64 + lane) * ROWB);
    const char* wbase = lds + (size_t)wid * 64 * ROWB;
    f32x4 acc[2][4];

    // ---- chunk 0, with chunk-1 gathers issued under chunk-0 compute ----
    Gath G0 = gather10(xb0, eld, g4);
    feats_to_lds(G0, rowv);
    Gath G1 = gather10(xb1, eld, g4n);      // lands under MFMA0 + epilogue0
    mfma_all(wbase, lo, hi, afrag, acc);
    epilogue<WSY>(acc, bat0, e0, wid, lane, lo, hi, lds, yb, yf, sacc);

    // ---- chunk 1 ----
    feats_to_lds(G1, rowv);
    mfma_all(wbase, lo, hi, afrag, acc);
    epilogue<WSY>(acc, bat1, e0, wid, lane, lo, hi, lds, yb, yf, sacc);

    __syncthreads();
    if (tid < 64)
        atomicAdd(&statsR[(bid & (NREP - 1)) * 64 + tid], sacc[tid >> 5][tid & 31]);
}

// BatchNorm (batch stats) + ReLU -> f32 output
template <bool WSY>
__global__ __launch_bounds__(256) void k_norm(const unsigned short* __restrict__ yb,
                                              float* __restrict__ yf,
                                              const float* __restrict__ statsR,
                                              const float* __restrict__ gamma,
                                              const float* __restrict__ beta) {
    int i = blockIdx.x * 256 + threadIdx.x;  // one per 8 elements
    if (i >= YELEMS / 8) return;
    int row = (int)(((long long)i * 8) / EDG);  // b*COUT + o
    int o = row & (COUT - 1);
    float s = 0.f, q = 0.f;
#pragma unroll
    for (int r = 0; r < NREP; ++r) {
        s += statsR[r * 64 + o];
        q += statsR[r * 64 + 32 + o];
    }
    const float inv_n = 1.0f / (float)NE;
    float mean = s * inv_n;
    float var = fmaf(-mean, mean, q * inv_n);
    float sc = gamma[o] * rsqrtf(var + EPS);
    float sh = fmaf(-mean, sc, beta[o]);

    float4 r0, r1;
    if constexpr (WSY) {
        us8 v = reinterpret_cast<const us8*>(yb)[i];
        float t[8];
#pragma unroll
        for (int k = 0; k < 8; ++k) t[k] = fmaxf(fmaf(bf2f(v[k]), sc, sh), 0.f);
        r0 = make_float4(t[0], t[1], t[2], t[3]);
        r1 = make_float4(t[4], t[5], t[6], t[7]);
    } else {
        float4 a = reinterpret_cast<float4*>(yf)[2 * i];
        float4 b = reinterpret_cast<float4*>(yf)[2 * i + 1];
        r0 = make_float4(fmaxf(fmaf(a.x, sc, sh), 0.f), fmaxf(fmaf(a.y, sc, sh), 0.f),
                         fmaxf(fmaf(a.z, sc, sh), 0.f), fmaxf(fmaf(a.w, sc, sh), 0.f));
        r1 = make_float4(fmaxf(fmaf(b.x, sc, sh), 0.f), fmaxf(fmaf(b.y, sc, sh), 0.f),
                         fmaxf(fmaf(b.z, sc, sh), 0.f), fmaxf(fmaf(b.w, sc, sh), 0.f));
    }
    reinterpret_cast<float4*>(yf)[2 * i] = r0;
    reinterpret_cast<float4*>(yf)[2 * i + 1] = r1;
}

extern "C" void kernel_launch(void* const* d_in, const int* in_sizes, int n_in,
                              void* d_out, int out_size, void* d_ws, size_t ws_size,
                              hipStream_t stream) {
    const float* x = (const float*)d_in[0];
    const int* gemm = (const int*)d_in[1];
    const float* w = (const float*)d_in[2];
    // d_in[3] = bias: cancels under BatchNorm, unused
    const float* gamma = (const float*)d_in[4];
    const float* beta = (const float*)d_in[5];

    float* yout = (float*)d_out;          // [B,COUT,E] f32
    float* gout = yout + YELEMS;          // [B,E,4] f32 mesh pass-through

    const size_t XT_BYTES = (size_t)NE * CIN * sizeof(unsigned short);   // 30.72 MB
    const size_t YB_BYTES = (size_t)YELEMS * sizeof(unsigned short);     // 61.44 MB

    unsigned short* xt = (unsigned short*)d_ws;
    bool wsy = ws_size >= XT_BYTES + YB_BYTES + 16384;
    char* tail = (char*)d_ws + XT_BYTES + (wsy ? YB_BYTES : 0);
    float* statsR = (float*)tail;                     // 16*64*4 = 4096 B
    s8v* afragG = (s8v*)(tail + 8192);                // 6144 B
    unsigned short* yb = (unsigned short*)((char*)d_ws + XT_BYTES);

    k_transpose<<<NE / 256, 256, 0, stream>>>(x, xt);
    k_wprep<<<1, 64, 0, stream>>>(w, afragG, statsR);
    if (wsy) {
        k_conv<true><<<8 * EBLKS, 256, 0, stream>>>(xt, gemm, afragG, yb, yout, gout, statsR);
        k_norm<true><<<YELEMS / 8 / 256, 256, 0, stream>>>(yb, yout, statsR, gamma, beta);
    } else {
        k_conv<false><<<8 * EBLKS, 256, 0, stream>>>(xt, gemm, afragG, yb, yout, gout, statsR);
        k_norm<false><<<YELEMS / 8 / 256, 256, 0, stream>>>(yb, yout, statsR, gamma, beta);
    }
}